// Round 9
// baseline (367.507 us; speedup 1.0000x reference)
//
#include <hip/hip_runtime.h>
#include <math.h>

#define NSNPS  500000
#define NGENES 20000
#define NNODES 600000
#define NEDGES 320000
#define BB     16
#define NFILT  8
#define NBLK2  5000   // gin grid = (NGENES/16)*4

// rsqrt(1 + 1e-5)
#define BN_SCALE 0.99999500003749968f

typedef unsigned short u16;

__device__ __forceinline__ float gelu_erf(float x) {
    return 0.5f * x * (1.0f + erff(x * 0.70710678118654752f));
}
__device__ __forceinline__ float sigmoidf_(float x) {
    return 1.0f / (1.0f + expf(-x));
}
// fp32 -> bf16 round-to-nearest-even
__device__ __forceinline__ u16 f2bf(float x) {
    unsigned u = __float_as_uint(x);
    u += 0x7fffu + ((u >> 16) & 1u);
    return (u16)(u >> 16);
}
__device__ __forceinline__ float bf1(u16 v)      { return __uint_as_float(((unsigned)v) << 16); }
__device__ __forceinline__ float bflo(unsigned v){ return __uint_as_float(v << 16); }
__device__ __forceinline__ float bfhi(unsigned v){ return __uint_as_float(v & 0xffff0000u); }
__device__ __forceinline__ unsigned pack2(float a, float b) {
    return (unsigned)f2bf(a) | ((unsigned)f2bf(b) << 16);
}

// ---------------------------------------------------------------------------
// Fused prep:
//  [A] filtersT bf16 + fp32 filters passthrough copy (one read of filters)
//  [B] snpT bf16
//  [C] node_off binary search + zero deg
#define PREP_NA 1954   // ceil(NSNPS/256)
#define PREP_NB 1954
#define PREP_NC 79     // ceil((NGENES+1)/256)
__global__ __launch_bounds__(256) void k_prep(const float* __restrict__ snp,
                                              const float* __restrict__ filters,
                                              const int* __restrict__ gene_of_node,
                                              u16* __restrict__ snpT,
                                              u16* __restrict__ filtT,
                                              float* __restrict__ out_filt,
                                              int* __restrict__ node_off,
                                              int* __restrict__ deg) {
    int bid = blockIdx.x;
    int t = threadIdx.x;
    if (bid < PREP_NA) {
        int n = bid * 256 + t;
        if (n < NSNPS) {
            float f0 = filters[0 * NSNPS + n], f1 = filters[1 * NSNPS + n];
            float f2 = filters[2 * NSNPS + n], f3 = filters[3 * NSNPS + n];
            float f4 = filters[4 * NSNPS + n], f5 = filters[5 * NSNPS + n];
            float f6 = filters[6 * NSNPS + n], f7 = filters[7 * NSNPS + n];
            uint4 p;
            p.x = pack2(f0, f1); p.y = pack2(f2, f3);
            p.z = pack2(f4, f5); p.w = pack2(f6, f7);
            *(uint4*)(filtT + (size_t)n * 8) = p;
            out_filt[0 * NSNPS + n] = f0; out_filt[1 * NSNPS + n] = f1;
            out_filt[2 * NSNPS + n] = f2; out_filt[3 * NSNPS + n] = f3;
            out_filt[4 * NSNPS + n] = f4; out_filt[5 * NSNPS + n] = f5;
            out_filt[6 * NSNPS + n] = f6; out_filt[7 * NSNPS + n] = f7;
        }
    } else if (bid < PREP_NA + PREP_NB) {
        int n = (bid - PREP_NA) * 256 + t;
        if (n < NSNPS) {
            uint4 p0, p1;
            p0.x = pack2(snp[0 * (size_t)NSNPS + n],  snp[1 * (size_t)NSNPS + n]);
            p0.y = pack2(snp[2 * (size_t)NSNPS + n],  snp[3 * (size_t)NSNPS + n]);
            p0.z = pack2(snp[4 * (size_t)NSNPS + n],  snp[5 * (size_t)NSNPS + n]);
            p0.w = pack2(snp[6 * (size_t)NSNPS + n],  snp[7 * (size_t)NSNPS + n]);
            p1.x = pack2(snp[8 * (size_t)NSNPS + n],  snp[9 * (size_t)NSNPS + n]);
            p1.y = pack2(snp[10 * (size_t)NSNPS + n], snp[11 * (size_t)NSNPS + n]);
            p1.z = pack2(snp[12 * (size_t)NSNPS + n], snp[13 * (size_t)NSNPS + n]);
            p1.w = pack2(snp[14 * (size_t)NSNPS + n], snp[15 * (size_t)NSNPS + n]);
            uint4* dst = (uint4*)(snpT + (size_t)n * 16);
            dst[0] = p0; dst[1] = p1;
        }
    } else {
        int g = (bid - PREP_NA - PREP_NB) * 256 + t;
        if (g < NGENES) deg[g] = 0;
        if (g <= NGENES) {
            int lo = 0, hi = NNODES;
            while (lo < hi) {
                int mid = (lo + hi) >> 1;
                if (gene_of_node[mid] < g) lo = mid + 1; else hi = mid;
            }
            node_off[g] = lo;
        }
    }
}

// ---------------------------------------------------------------------------
__global__ __launch_bounds__(256) void k_deg(const int* __restrict__ edge_dst,
                                             int* __restrict__ deg) {
    int e = blockIdx.x * 256 + threadIdx.x;
    if (e >= NEDGES) return;
    atomicAdd(&deg[edge_dst[e]], 1);
}

__global__ __launch_bounds__(1024) void k_scan(const int* __restrict__ deg,
                                               int* __restrict__ csr_off,
                                               int* __restrict__ cursor) {
    __shared__ int sums[1024];
    int t = threadIdx.x;
    const int CH = (NGENES + 1023) / 1024;   // 20
    int base = t * CH;
    int s = 0;
    for (int i = 0; i < CH; i++) {
        int idx = base + i;
        if (idx < NGENES) s += deg[idx];
    }
    sums[t] = s;
    __syncthreads();
    for (int off = 1; off < 1024; off <<= 1) {
        int v = (t >= off) ? sums[t - off] : 0;
        __syncthreads();
        sums[t] += v;
        __syncthreads();
    }
    int run = (t == 0) ? 0 : sums[t - 1];
    for (int i = 0; i < CH; i++) {
        int idx = base + i;
        if (idx < NGENES) {
            csr_off[idx] = run;
            cursor[idx]  = run;
            run += deg[idx];
        }
    }
    if (t == 1023) csr_off[NGENES] = sums[1023];
}

__global__ __launch_bounds__(256) void k_scatter(const int* __restrict__ edge_src,
                                                 const int* __restrict__ edge_dst,
                                                 int* __restrict__ cursor,
                                                 int* __restrict__ csr_src) {
    int e = blockIdx.x * 256 + threadIdx.x;
    if (e >= NEDGES) return;
    int p = atomicAdd(&cursor[edge_dst[e]], 1);
    csr_src[p] = edge_src[e];
}

// ---------------------------------------------------------------------------
// SNP->gene (bf16): FOUR waves per gene, 1 gene per block. lane = sub4*16 + b,
// global sub = wave*4 + sub4 in [0,16), stride 16. 4-way LDS combine.
__global__ __launch_bounds__(256) void k_snp2gene(const u16* __restrict__ snpT,
                                                  const int* __restrict__ snp_ids,
                                                  const int* __restrict__ node_off,
                                                  const u16* __restrict__ filtT,
                                                  u16* __restrict__ h_bf) {
    __shared__ float sZ[4][128];
    int t = threadIdx.x;
    int wave = t >> 6, lane = t & 63;
    int g = blockIdx.x;
    int sub = (wave << 2) + (lane >> 4);     // 0..15
    int b = lane & 15;
    int s = node_off[g], e = node_off[g + 1];

    float acc[8];
    #pragma unroll
    for (int f = 0; f < 8; f++) acc[f] = 0.0f;

    int i = s + sub;
    for (; i + 16 < e; i += 32) {
        int id0 = snp_ids[i];
        int id1 = snp_ids[i + 16];
        float v0 = bf1(snpT[(size_t)id0 * 16 + b]);
        float v1 = bf1(snpT[(size_t)id1 * 16 + b]);
        uint4 F0 = *(const uint4*)(filtT + (size_t)id0 * 8);
        uint4 F1 = *(const uint4*)(filtT + (size_t)id1 * 8);
        acc[0] += v0 * bflo(F0.x) + v1 * bflo(F1.x);
        acc[1] += v0 * bfhi(F0.x) + v1 * bfhi(F1.x);
        acc[2] += v0 * bflo(F0.y) + v1 * bflo(F1.y);
        acc[3] += v0 * bfhi(F0.y) + v1 * bfhi(F1.y);
        acc[4] += v0 * bflo(F0.z) + v1 * bflo(F1.z);
        acc[5] += v0 * bfhi(F0.z) + v1 * bfhi(F1.z);
        acc[6] += v0 * bflo(F0.w) + v1 * bflo(F1.w);
        acc[7] += v0 * bfhi(F0.w) + v1 * bfhi(F1.w);
    }
    if (i < e) {
        int id0 = snp_ids[i];
        float v0 = bf1(snpT[(size_t)id0 * 16 + b]);
        uint4 F0 = *(const uint4*)(filtT + (size_t)id0 * 8);
        acc[0] += v0 * bflo(F0.x); acc[1] += v0 * bfhi(F0.x);
        acc[2] += v0 * bflo(F0.y); acc[3] += v0 * bfhi(F0.y);
        acc[4] += v0 * bflo(F0.z); acc[5] += v0 * bfhi(F0.z);
        acc[6] += v0 * bflo(F0.w); acc[7] += v0 * bfhi(F0.w);
    }
    #pragma unroll
    for (int f = 0; f < 8; f++) {
        acc[f] += __shfl_xor(acc[f], 16, 64);
        acc[f] += __shfl_xor(acc[f], 32, 64);
    }
    if (lane < 16) {   // lane == b
        float* dst = &sZ[wave][lane * 8];
        *(float4*)(dst)     = make_float4(acc[0], acc[1], acc[2], acc[3]);
        *(float4*)(dst + 4) = make_float4(acc[4], acc[5], acc[6], acc[7]);
    }
    __syncthreads();
    if (t < 128) {
        float val = sZ[0][t] + sZ[1][t] + sZ[2][t] + sZ[3][t];
        h_bf[(size_t)g * 128 + t] = f2bf(val);
    }
}

// ---------------------------------------------------------------------------
// Fused GIN layer 1: chunked agg (bf16, L2-resident slice) + MLP.
// Block = 16 genes x 16 threads; chunk = blockIdx&3. Per gene: 2 edge-halves
// (stride-2 interleave) x 8 col-positions. half combine via shfl_xor(8),
// col-half (fh) exchange via shfl_xor(1). MLP j-split over 4 threads/row.
__global__ __launch_bounds__(256) void k_gin1(const u16* __restrict__ hin,   // [g][128]
                                              u16* __restrict__ hout,        // [g][128]
                                              const int* __restrict__ csr_off,
                                              const int* __restrict__ csr_src,
                                              const float* __restrict__ eps_l,
                                              const float* __restrict__ W1,
                                              const float* __restrict__ b1,
                                              const float* __restrict__ g1,
                                              const float* __restrict__ bt1,
                                              const float* __restrict__ W2,
                                              const float* __restrict__ b2,
                                              const float* __restrict__ g2,
                                              const float* __restrict__ bt2) {
    __shared__ float sW1[128], sb1[16], sg1[16], sbt1[16];
    __shared__ float sW2[128], sb2[8], sg2[8], sbt2[8];
    int t = threadIdx.x;
    if (t < 128) { sW1[t] = W1[t]; sW2[t] = W2[t]; }
    if (t < 16)  { sb1[t] = b1[t]; sg1[t] = g1[t]; sbt1[t] = bt1[t]; }
    if (t < 8)   { sb2[t] = b2[t]; sg2[t] = g2[t]; sbt2[t] = bt2[t]; }

    int chunk = blockIdx.x & 3;
    int g = (blockIdx.x >> 2) * 16 + (t >> 4);
    int u = t & 15;
    int half = u >> 3;                       // edge-range half
    int colpos = u & 7;
    int fh = colpos & 1;                     // f-half: 0 -> f0..3, 1 -> f4..7
    int jgroup = half * 2 + fh;              // 0..3, MLP hidden-unit group
    int col = chunk * 32 + colpos * 4;
    const u16* __restrict__ hc = hin + col;
    float epsv = 1.0f + eps_l[0];

    float a0, a1, a2, a3;
    if (half == 0) {   // self term only once
        uint2 su = *(const uint2*)(hc + (size_t)g * 128);
        a0 = bflo(su.x) * epsv; a1 = bfhi(su.x) * epsv;
        a2 = bflo(su.y) * epsv; a3 = bfhi(su.y) * epsv;
    } else {
        a0 = a1 = a2 = a3 = 0.0f;
    }

    int s = csr_off[g], e = csr_off[g + 1];
    int k = s + half;
    for (; k + 14 < e; k += 16) {   // 8 edges per half, stride 2
        int i0 = csr_src[k],      i1 = csr_src[k + 2];
        int i2 = csr_src[k + 4],  i3 = csr_src[k + 6];
        int i4 = csr_src[k + 8],  i5 = csr_src[k + 10];
        int i6 = csr_src[k + 12], i7 = csr_src[k + 14];
        uint2 v0 = *(const uint2*)(hc + (size_t)i0 * 128);
        uint2 v1 = *(const uint2*)(hc + (size_t)i1 * 128);
        uint2 v2 = *(const uint2*)(hc + (size_t)i2 * 128);
        uint2 v3 = *(const uint2*)(hc + (size_t)i3 * 128);
        uint2 v4 = *(const uint2*)(hc + (size_t)i4 * 128);
        uint2 v5 = *(const uint2*)(hc + (size_t)i5 * 128);
        uint2 v6 = *(const uint2*)(hc + (size_t)i6 * 128);
        uint2 v7 = *(const uint2*)(hc + (size_t)i7 * 128);
        a0 += ((bflo(v0.x) + bflo(v1.x)) + (bflo(v2.x) + bflo(v3.x)))
            + ((bflo(v4.x) + bflo(v5.x)) + (bflo(v6.x) + bflo(v7.x)));
        a1 += ((bfhi(v0.x) + bfhi(v1.x)) + (bfhi(v2.x) + bfhi(v3.x)))
            + ((bfhi(v4.x) + bfhi(v5.x)) + (bfhi(v6.x) + bfhi(v7.x)));
        a2 += ((bflo(v0.y) + bflo(v1.y)) + (bflo(v2.y) + bflo(v3.y)))
            + ((bflo(v4.y) + bflo(v5.y)) + (bflo(v6.y) + bflo(v7.y)));
        a3 += ((bfhi(v0.y) + bfhi(v1.y)) + (bfhi(v2.y) + bfhi(v3.y)))
            + ((bfhi(v4.y) + bfhi(v5.y)) + (bfhi(v6.y) + bfhi(v7.y)));
    }
    for (; k < e; k += 2) {
        int i0 = csr_src[k];
        uint2 v0 = *(const uint2*)(hc + (size_t)i0 * 128);
        a0 += bflo(v0.x); a1 += bfhi(v0.x);
        a2 += bflo(v0.y); a3 += bfhi(v0.y);
    }
    __syncthreads();   // weights visible

    // combine edge halves (lane bit 3)
    a0 += __shfl_xor(a0, 8, 64);
    a1 += __shfl_xor(a1, 8, 64);
    a2 += __shfl_xor(a2, 8, 64);
    a3 += __shfl_xor(a3, 8, 64);
    // exchange col-halves (lane bit 0) to build full z[8]
    float p0 = __shfl_xor(a0, 1, 64);
    float p1 = __shfl_xor(a1, 1, 64);
    float p2 = __shfl_xor(a2, 1, 64);
    float p3 = __shfl_xor(a3, 1, 64);
    float z[8];
    z[fh * 4 + 0] = a0; z[fh * 4 + 1] = a1; z[fh * 4 + 2] = a2; z[fh * 4 + 3] = a3;
    z[(1 - fh) * 4 + 0] = p0; z[(1 - fh) * 4 + 1] = p1;
    z[(1 - fh) * 4 + 2] = p2; z[(1 - fh) * 4 + 3] = p3;

    // split-j MLP: this thread handles hidden units j in [jgroup*4, jgroup*4+4)
    float op[8];
    #pragma unroll
    for (int f = 0; f < 8; f++) op[f] = (jgroup == 0) ? sb2[f] : 0.0f;
    #pragma unroll
    for (int jj = 0; jj < 4; jj++) {
        int j = jgroup * 4 + jj;
        float s1 = sb1[j];
        #pragma unroll
        for (int i2 = 0; i2 < 8; i2++) s1 += z[i2] * sW1[i2 * 16 + j];
        s1 = s1 * BN_SCALE * sg1[j] + sbt1[j];
        s1 = gelu_erf(s1);
        #pragma unroll
        for (int f = 0; f < 8; f++) op[f] += s1 * sW2[j * 8 + f];
    }
    // combine partial outputs over the 4 row-threads, finalize own 4 f's
    float r[4];
    #pragma unroll
    for (int fi = 0; fi < 4; fi++) {
        int f = fh * 4 + fi;
        float x = op[f] + __shfl_xor(op[f], 1, 64);
        x += __shfl_xor(x, 8, 64);
        r[fi] = gelu_erf(x * BN_SCALE * sg2[f] + sbt2[f]);
    }
    if (half == 0) {
        uint2 ou;
        ou.x = pack2(r[0], r[1]); ou.y = pack2(r[2], r[3]);
        *(uint2*)(hout + (size_t)g * 128 + col) = ou;
    }
}

// ---------------------------------------------------------------------------
// Fused GIN layer 2 + attentive readout (no atomics; per-block partials).
__global__ __launch_bounds__(256) void k_gin2(const u16* __restrict__ hin,
                                              const int* __restrict__ csr_off,
                                              const int* __restrict__ csr_src,
                                              const float* __restrict__ eps_l,
                                              const float* __restrict__ W1,
                                              const float* __restrict__ b1,
                                              const float* __restrict__ g1,
                                              const float* __restrict__ bt1,
                                              const float* __restrict__ W2,
                                              const float* __restrict__ b2,
                                              const float* __restrict__ g2,
                                              const float* __restrict__ bt2,
                                              const float* __restrict__ Wk,
                                              const float* __restrict__ bk,
                                              const float* __restrict__ Wq,
                                              const float* __restrict__ Wv,
                                              const float* __restrict__ bv,
                                              float* __restrict__ w_out,    // [b][g]
                                              float* __restrict__ partial) { // [NBLK2][32]
    __shared__ float sW1[128], sb1[16], sg1[16], sbt1[16];
    __shared__ float sW2[128], sb2[8], sg2[8], sbt2[8];
    __shared__ float sWk[64], sWv[64], sbk[8], sbv[8], sWq[8];
    __shared__ float sRed[4][4][8];
    int t = threadIdx.x;
    if (t < 128) { sW1[t] = W1[t]; sW2[t] = W2[t]; }
    if (t < 64)  { sWk[t] = Wk[t]; sWv[t] = Wv[t]; }
    if (t < 16)  { sb1[t] = b1[t]; sg1[t] = g1[t]; sbt1[t] = bt1[t]; }
    if (t < 8)   { sb2[t] = b2[t]; sg2[t] = g2[t]; sbt2[t] = bt2[t];
                   sbk[t] = bk[t]; sbv[t] = bv[t]; sWq[t] = Wq[t]; }

    int chunk = blockIdx.x & 3;
    int g = (blockIdx.x >> 2) * 16 + (t >> 4);
    int u = t & 15;
    int half = u >> 3;
    int colpos = u & 7;
    int fh = colpos & 1;
    int jgroup = half * 2 + fh;
    int b = chunk * 4 + (colpos >> 1);
    int col = chunk * 32 + colpos * 4;
    const u16* __restrict__ hc = hin + col;
    float epsv = 1.0f + eps_l[0];

    float a0, a1, a2, a3;
    if (half == 0) {
        uint2 su = *(const uint2*)(hc + (size_t)g * 128);
        a0 = bflo(su.x) * epsv; a1 = bfhi(su.x) * epsv;
        a2 = bflo(su.y) * epsv; a3 = bfhi(su.y) * epsv;
    } else {
        a0 = a1 = a2 = a3 = 0.0f;
    }

    int s = csr_off[g], e = csr_off[g + 1];
    int k = s + half;
    for (; k + 14 < e; k += 16) {
        int i0 = csr_src[k],      i1 = csr_src[k + 2];
        int i2 = csr_src[k + 4],  i3 = csr_src[k + 6];
        int i4 = csr_src[k + 8],  i5 = csr_src[k + 10];
        int i6 = csr_src[k + 12], i7 = csr_src[k + 14];
        uint2 v0 = *(const uint2*)(hc + (size_t)i0 * 128);
        uint2 v1 = *(const uint2*)(hc + (size_t)i1 * 128);
        uint2 v2 = *(const uint2*)(hc + (size_t)i2 * 128);
        uint2 v3 = *(const uint2*)(hc + (size_t)i3 * 128);
        uint2 v4 = *(const uint2*)(hc + (size_t)i4 * 128);
        uint2 v5 = *(const uint2*)(hc + (size_t)i5 * 128);
        uint2 v6 = *(const uint2*)(hc + (size_t)i6 * 128);
        uint2 v7 = *(const uint2*)(hc + (size_t)i7 * 128);
        a0 += ((bflo(v0.x) + bflo(v1.x)) + (bflo(v2.x) + bflo(v3.x)))
            + ((bflo(v4.x) + bflo(v5.x)) + (bflo(v6.x) + bflo(v7.x)));
        a1 += ((bfhi(v0.x) + bfhi(v1.x)) + (bfhi(v2.x) + bfhi(v3.x)))
            + ((bfhi(v4.x) + bfhi(v5.x)) + (bfhi(v6.x) + bfhi(v7.x)));
        a2 += ((bflo(v0.y) + bflo(v1.y)) + (bflo(v2.y) + bflo(v3.y)))
            + ((bflo(v4.y) + bflo(v5.y)) + (bflo(v6.y) + bflo(v7.y)));
        a3 += ((bfhi(v0.y) + bfhi(v1.y)) + (bfhi(v2.y) + bfhi(v3.y)))
            + ((bfhi(v4.y) + bfhi(v5.y)) + (bfhi(v6.y) + bfhi(v7.y)));
    }
    for (; k < e; k += 2) {
        int i0 = csr_src[k];
        uint2 v0 = *(const uint2*)(hc + (size_t)i0 * 128);
        a0 += bflo(v0.x); a1 += bfhi(v0.x);
        a2 += bflo(v0.y); a3 += bfhi(v0.y);
    }
    __syncthreads();

    a0 += __shfl_xor(a0, 8, 64);
    a1 += __shfl_xor(a1, 8, 64);
    a2 += __shfl_xor(a2, 8, 64);
    a3 += __shfl_xor(a3, 8, 64);
    float p0 = __shfl_xor(a0, 1, 64);
    float p1 = __shfl_xor(a1, 1, 64);
    float p2 = __shfl_xor(a2, 1, 64);
    float p3 = __shfl_xor(a3, 1, 64);
    float z[8];
    z[fh * 4 + 0] = a0; z[fh * 4 + 1] = a1; z[fh * 4 + 2] = a2; z[fh * 4 + 3] = a3;
    z[(1 - fh) * 4 + 0] = p0; z[(1 - fh) * 4 + 1] = p1;
    z[(1 - fh) * 4 + 2] = p2; z[(1 - fh) * 4 + 3] = p3;

    // split-j MLP (4 hidden units per thread)
    float op[8];
    #pragma unroll
    for (int f = 0; f < 8; f++) op[f] = (jgroup == 0) ? sb2[f] : 0.0f;
    #pragma unroll
    for (int jj = 0; jj < 4; jj++) {
        int j = jgroup * 4 + jj;
        float s1 = sb1[j];
        #pragma unroll
        for (int i2 = 0; i2 < 8; i2++) s1 += z[i2] * sW1[i2 * 16 + j];
        s1 = s1 * BN_SCALE * sg1[j] + sbt1[j];
        s1 = gelu_erf(s1);
        #pragma unroll
        for (int f = 0; f < 8; f++) op[f] += s1 * sW2[j * 8 + f];
    }
    // combine, finalize own f-half, exchange to get full hv[8]
    float hvh[4];
    #pragma unroll
    for (int fi = 0; fi < 4; fi++) {
        int f = fh * 4 + fi;
        float x = op[f] + __shfl_xor(op[f], 1, 64);
        x += __shfl_xor(x, 8, 64);
        hvh[fi] = gelu_erf(x * BN_SCALE * sg2[f] + sbt2[f]);
    }
    float hv[8];
    #pragma unroll
    for (int fi = 0; fi < 4; fi++) {
        hv[fh * 4 + fi] = hvh[fi];
        hv[(1 - fh) * 4 + fi] = __shfl_xor(hvh[fi], 1, 64);
    }

    // readout: q split over 4 threads (2 j's each)
    float qp = 0.0f;
    #pragma unroll
    for (int jj = 0; jj < 2; jj++) {
        int j = jgroup * 2 + jj;
        float key = sbk[j];
        #pragma unroll
        for (int i2 = 0; i2 < 8; i2++) key += hv[i2] * sWk[i2 * 8 + j];
        qp += key * sWq[j];
    }
    float q = qp + __shfl_xor(qp, 1, 64);
    q += __shfl_xor(q, 8, 64);
    float w = sigmoidf_(q);
    if (fh == 0 && half == 0) w_out[(size_t)b * NGENES + g] = w;

    // value contribution: own f-half; half 1 zeroed (avoid double count)
    float contrib[4];
    #pragma unroll
    for (int fi = 0; fi < 4; fi++) {
        int f = fh * 4 + fi;
        float v = sbv[f];
        #pragma unroll
        for (int i2 = 0; i2 < 8; i2++) v += hv[i2] * sWv[i2 * 8 + f];
        contrib[fi] = (half == 0) ? v * w : 0.0f;
    }
    // reduce over halves (xor8) and the 4 genes in the wave (xor 16,32)
    #pragma unroll
    for (int fi = 0; fi < 4; fi++) {
        contrib[fi] += __shfl_xor(contrib[fi], 8, 64);
        contrib[fi] += __shfl_xor(contrib[fi], 16, 64);
        contrib[fi] += __shfl_xor(contrib[fi], 32, 64);
    }
    int wave = t >> 6, lane = t & 63;
    if (lane < 8) {
        #pragma unroll
        for (int fi = 0; fi < 4; fi++)
            sRed[wave][lane >> 1][(lane & 1) * 4 + fi] = contrib[fi];
    }
    __syncthreads();
    if (t < 32) {   // 4 local batches x 8 filters -> plain store (NO atomics)
        int bl = t >> 3, f = t & 7;
        float sm = sRed[0][bl][f] + sRed[1][bl][f] + sRed[2][bl][f] + sRed[3][bl][f];
        partial[(size_t)blockIdx.x * 32 + bl * 8 + f] = sm;
    }
}

// ---------------------------------------------------------------------------
// Head MLP. Phase 0 reduces the per-block readout partials (no atomics).
__global__ __launch_bounds__(1024) void k_head(const float* __restrict__ partial, // [NBLK2][32]
                                               const float* __restrict__ Wp1, const float* __restrict__ bp1,
                                               const float* __restrict__ gp1, const float* __restrict__ btp1,
                                               const float* __restrict__ Wp2, const float* __restrict__ bp2,
                                               const float* __restrict__ gp2, const float* __restrict__ btp2,
                                               const float* __restrict__ Wp3, const float* __restrict__ bp3,
                                               float* __restrict__ preds) {
    __shared__ float sgh[128];
    __shared__ float red[1024];
    __shared__ float z1[16 * 64];
    __shared__ float z2[16 * 16];
    int t = threadIdx.x;
    // phase 0: g_h[b*8+f] = sum over blocks with chunk == b>>2
    {
        int bf = t >> 3;            // 0..127 = b*8+f
        int ln = t & 7;
        int b = bf >> 3, f = bf & 7;
        int c = b >> 2, bl = b & 3;
        float s = 0.0f;
        for (int j = ln; j < NBLK2 / 4; j += 8)     // 1250 blocks per chunk
            s += partial[(size_t)(c + 4 * j) * 32 + bl * 8 + f];
        red[t] = s;
    }
    __syncthreads();
    if ((t & 7) == 0) {
        int bf = t >> 3;
        float tot = 0.0f;
        #pragma unroll
        for (int k = 0; k < 8; k++) tot += red[(bf << 3) + k];
        sgh[bf] = tot;
    }
    __syncthreads();
    {
        int b = t >> 6, j = t & 63;
        float s = bp1[j];
        #pragma unroll
        for (int k = 0; k < 8; k++) s += sgh[b * 8 + k] * Wp1[k * 64 + j];
        s = s * BN_SCALE * gp1[j] + btp1[j];
        z1[b * 64 + j] = gelu_erf(s);
    }
    __syncthreads();
    if (t < 256) {
        int b = t >> 4, j = t & 15;
        float s = bp2[j];
        for (int k = 0; k < 64; k++) s += z1[b * 64 + k] * Wp2[k * 16 + j];
        s = s * BN_SCALE * gp2[j] + btp2[j];
        z2[b * 16 + j] = gelu_erf(s);
    }
    __syncthreads();
    if (t < 16) {
        float s = bp3[0];
        #pragma unroll
        for (int k = 0; k < 16; k++) s += z2[t * 16 + k] * Wp3[k];
        preds[t] = s;
    }
}

// ---------------------------------------------------------------------------
extern "C" void kernel_launch(void* const* d_in, const int* in_sizes, int n_in,
                              void* d_out, int out_size, void* d_ws, size_t ws_size,
                              hipStream_t stream) {
    const float* snp          = (const float*)d_in[0];
    const int*   snp_ids      = (const int*)  d_in[1];
    const int*   gene_of_node = (const int*)  d_in[2];
    const int*   edge_src     = (const int*)  d_in[3];
    const int*   edge_dst     = (const int*)  d_in[4];
    const float* filters      = (const float*)d_in[5];
    const float* eps          = (const float*)d_in[6];
    const float* W1  = (const float*)d_in[7];
    const float* b1  = (const float*)d_in[8];
    const float* g1  = (const float*)d_in[9];
    const float* bt1 = (const float*)d_in[10];
    const float* W2  = (const float*)d_in[11];
    const float* b2  = (const float*)d_in[12];
    const float* g2  = (const float*)d_in[13];
    const float* bt2 = (const float*)d_in[14];
    const float* Wk  = (const float*)d_in[15];
    const float* bk  = (const float*)d_in[16];
    const float* Wq  = (const float*)d_in[17];
    const float* Wv  = (const float*)d_in[18];
    const float* bv  = (const float*)d_in[19];
    const float* Wp1 = (const float*)d_in[20];
    const float* bp1 = (const float*)d_in[21];
    const float* gp1 = (const float*)d_in[22];
    const float* btp1= (const float*)d_in[23];
    const float* Wp2 = (const float*)d_in[24];
    const float* bp2 = (const float*)d_in[25];
    const float* gp2 = (const float*)d_in[26];
    const float* btp2= (const float*)d_in[27];
    const float* Wp3 = (const float*)d_in[28];
    const float* bp3 = (const float*)d_in[29];

    float* out        = (float*)d_out;
    float* out_preds  = out;
    float* out_filt   = out + 16;
    float* out_w      = out + 16 + NFILT * NSNPS;

    // ---- workspace layout
    char* ws = (char*)d_ws;
    size_t off = 0;
    u16* snpT = (u16*)(ws + off); off += (size_t)NSNPS * 16 * 2;                 // 16 MB
    u16* filtT= (u16*)(ws + off); off += (size_t)NSNPS * 8 * 2;                  // 8 MB
    u16* h0   = (u16*)(ws + off); off += (size_t)NGENES * 128 * 2;               // 5.12 MB
    u16* h1   = (u16*)(ws + off); off += (size_t)NGENES * 128 * 2;               // 5.12 MB
    int* node_off = (int*)(ws + off); off += ((NGENES + 1) * 4 + 255) / 256 * 256;
    int* deg      = (int*)(ws + off); off += (NGENES * 4 + 255) / 256 * 256;
    int* csr_off  = (int*)(ws + off); off += ((NGENES + 1) * 4 + 255) / 256 * 256;
    int* cursor   = (int*)(ws + off); off += (NGENES * 4 + 255) / 256 * 256;
    int* csr_src  = (int*)(ws + off); off += (size_t)NEDGES * 4;
    float* partial= (float*)(ws + off); off += (size_t)NBLK2 * 32 * 4;           // 640 KB

    // 1. fused prep (filtersT + fp32 copy, snpT, node_off + deg zeroing)
    k_prep<<<PREP_NA + PREP_NB + PREP_NC, 256, 0, stream>>>(
        snp, filters, gene_of_node, snpT, filtT, out_filt, node_off, deg);
    // 2. CSR build
    k_deg<<<(NEDGES + 255) / 256, 256, 0, stream>>>(edge_dst, deg);
    k_scan<<<1, 1024, 0, stream>>>(deg, csr_off, cursor);
    k_scatter<<<(NEDGES + 255) / 256, 256, 0, stream>>>(edge_src, edge_dst, cursor, csr_src);
    // 3. SNP -> gene readout (4 waves/gene)
    k_snp2gene<<<NGENES, 256, 0, stream>>>(snpT, snp_ids, node_off, filtT, h0);
    // 4. GIN layer 1 (16 threads/gene: edge-halved gather + split-j MLP)
    k_gin1<<<NBLK2, 256, 0, stream>>>(h0, h1, csr_off, csr_src, eps + 0,
                                      W1 + 0 * 128, b1 + 0 * 16, g1 + 0 * 16, bt1 + 0 * 16,
                                      W2 + 0 * 128, b2 + 0 * 8, g2 + 0 * 8, bt2 + 0 * 8);
    // 5. GIN layer 2 + attentive readout (no atomics)
    k_gin2<<<NBLK2, 256, 0, stream>>>(h1, csr_off, csr_src, eps + 1,
                                      W1 + 1 * 128, b1 + 1 * 16, g1 + 1 * 16, bt1 + 1 * 16,
                                      W2 + 1 * 128, b2 + 1 * 8, g2 + 1 * 8, bt2 + 1 * 8,
                                      Wk, bk, Wq, Wv, bv, out_w, partial);
    // 6. head MLP (reduces partials in phase 0)
    k_head<<<1, 1024, 0, stream>>>(partial, Wp1, bp1, gp1, btp1, Wp2, bp2, gp2, btp2, Wp3, bp3, out_preds);
}

// Round 10
// 330.821 us; speedup vs baseline: 1.1109x; 1.1109x over previous
//
#include <hip/hip_runtime.h>
#include <math.h>

#define NSNPS  500000
#define NGENES 20000
#define NNODES 600000
#define NEDGES 320000
#define BB     16
#define NFILT  8
#define NBLK2  5000   // gin grid = (NGENES/16)*4

// rsqrt(1 + 1e-5)
#define BN_SCALE 0.99999500003749968f

typedef unsigned short u16;

__device__ __forceinline__ float gelu_erf(float x) {
    return 0.5f * x * (1.0f + erff(x * 0.70710678118654752f));
}
__device__ __forceinline__ float sigmoidf_(float x) {
    return 1.0f / (1.0f + expf(-x));
}
// fp32 -> bf16 round-to-nearest-even
__device__ __forceinline__ u16 f2bf(float x) {
    unsigned u = __float_as_uint(x);
    u += 0x7fffu + ((u >> 16) & 1u);
    return (u16)(u >> 16);
}
__device__ __forceinline__ float bf1(u16 v)      { return __uint_as_float(((unsigned)v) << 16); }
__device__ __forceinline__ float bflo(unsigned v){ return __uint_as_float(v << 16); }
__device__ __forceinline__ float bfhi(unsigned v){ return __uint_as_float(v & 0xffff0000u); }
__device__ __forceinline__ unsigned pack2(float a, float b) {
    return (unsigned)f2bf(a) | ((unsigned)f2bf(b) << 16);
}

// ---------------------------------------------------------------------------
// Fused prep:
//  [A] filtersT bf16 + fp32 filters passthrough copy (one read of filters)
//  [B] snpT bf16
//  [C] node_off binary search + zero deg
#define PREP_NA 1954   // ceil(NSNPS/256)
#define PREP_NB 1954
#define PREP_NC 79     // ceil((NGENES+1)/256)
__global__ __launch_bounds__(256) void k_prep(const float* __restrict__ snp,
                                              const float* __restrict__ filters,
                                              const int* __restrict__ gene_of_node,
                                              u16* __restrict__ snpT,
                                              u16* __restrict__ filtT,
                                              float* __restrict__ out_filt,
                                              int* __restrict__ node_off,
                                              int* __restrict__ deg) {
    int bid = blockIdx.x;
    int t = threadIdx.x;
    if (bid < PREP_NA) {
        int n = bid * 256 + t;
        if (n < NSNPS) {
            float f0 = filters[0 * NSNPS + n], f1 = filters[1 * NSNPS + n];
            float f2 = filters[2 * NSNPS + n], f3 = filters[3 * NSNPS + n];
            float f4 = filters[4 * NSNPS + n], f5 = filters[5 * NSNPS + n];
            float f6 = filters[6 * NSNPS + n], f7 = filters[7 * NSNPS + n];
            uint4 p;
            p.x = pack2(f0, f1); p.y = pack2(f2, f3);
            p.z = pack2(f4, f5); p.w = pack2(f6, f7);
            *(uint4*)(filtT + (size_t)n * 8) = p;
            out_filt[0 * NSNPS + n] = f0; out_filt[1 * NSNPS + n] = f1;
            out_filt[2 * NSNPS + n] = f2; out_filt[3 * NSNPS + n] = f3;
            out_filt[4 * NSNPS + n] = f4; out_filt[5 * NSNPS + n] = f5;
            out_filt[6 * NSNPS + n] = f6; out_filt[7 * NSNPS + n] = f7;
        }
    } else if (bid < PREP_NA + PREP_NB) {
        int n = (bid - PREP_NA) * 256 + t;
        if (n < NSNPS) {
            uint4 p0, p1;
            p0.x = pack2(snp[0 * (size_t)NSNPS + n],  snp[1 * (size_t)NSNPS + n]);
            p0.y = pack2(snp[2 * (size_t)NSNPS + n],  snp[3 * (size_t)NSNPS + n]);
            p0.z = pack2(snp[4 * (size_t)NSNPS + n],  snp[5 * (size_t)NSNPS + n]);
            p0.w = pack2(snp[6 * (size_t)NSNPS + n],  snp[7 * (size_t)NSNPS + n]);
            p1.x = pack2(snp[8 * (size_t)NSNPS + n],  snp[9 * (size_t)NSNPS + n]);
            p1.y = pack2(snp[10 * (size_t)NSNPS + n], snp[11 * (size_t)NSNPS + n]);
            p1.z = pack2(snp[12 * (size_t)NSNPS + n], snp[13 * (size_t)NSNPS + n]);
            p1.w = pack2(snp[14 * (size_t)NSNPS + n], snp[15 * (size_t)NSNPS + n]);
            uint4* dst = (uint4*)(snpT + (size_t)n * 16);
            dst[0] = p0; dst[1] = p1;
        }
    } else {
        int g = (bid - PREP_NA - PREP_NB) * 256 + t;
        if (g < NGENES) deg[g] = 0;
        if (g <= NGENES) {
            int lo = 0, hi = NNODES;
            while (lo < hi) {
                int mid = (lo + hi) >> 1;
                if (gene_of_node[mid] < g) lo = mid + 1; else hi = mid;
            }
            node_off[g] = lo;
        }
    }
}

// ---------------------------------------------------------------------------
__global__ __launch_bounds__(256) void k_deg(const int* __restrict__ edge_dst,
                                             int* __restrict__ deg) {
    int e = blockIdx.x * 256 + threadIdx.x;
    if (e >= NEDGES) return;
    atomicAdd(&deg[edge_dst[e]], 1);
}

__global__ __launch_bounds__(1024) void k_scan(const int* __restrict__ deg,
                                               int* __restrict__ csr_off,
                                               int* __restrict__ cursor) {
    __shared__ int sums[1024];
    int t = threadIdx.x;
    const int CH = (NGENES + 1023) / 1024;   // 20
    int base = t * CH;
    int s = 0;
    for (int i = 0; i < CH; i++) {
        int idx = base + i;
        if (idx < NGENES) s += deg[idx];
    }
    sums[t] = s;
    __syncthreads();
    for (int off = 1; off < 1024; off <<= 1) {
        int v = (t >= off) ? sums[t - off] : 0;
        __syncthreads();
        sums[t] += v;
        __syncthreads();
    }
    int run = (t == 0) ? 0 : sums[t - 1];
    for (int i = 0; i < CH; i++) {
        int idx = base + i;
        if (idx < NGENES) {
            csr_off[idx] = run;
            cursor[idx]  = run;
            run += deg[idx];
        }
    }
    if (t == 1023) csr_off[NGENES] = sums[1023];
}

__global__ __launch_bounds__(256) void k_scatter(const int* __restrict__ edge_src,
                                                 const int* __restrict__ edge_dst,
                                                 int* __restrict__ cursor,
                                                 int* __restrict__ csr_src) {
    int e = blockIdx.x * 256 + threadIdx.x;
    if (e >= NEDGES) return;
    int p = atomicAdd(&cursor[edge_dst[e]], 1);
    csr_src[p] = edge_src[e];
}

// ---------------------------------------------------------------------------
// SNP->gene (bf16): FOUR waves per gene, 1 gene per block. lane = sub4*16 + b,
// global sub = wave*4 + sub4 in [0,16), stride 16. 4-way LDS combine.
__global__ __launch_bounds__(256) void k_snp2gene(const u16* __restrict__ snpT,
                                                  const int* __restrict__ snp_ids,
                                                  const int* __restrict__ node_off,
                                                  const u16* __restrict__ filtT,
                                                  u16* __restrict__ h_bf) {
    __shared__ float sZ[4][128];
    int t = threadIdx.x;
    int wave = t >> 6, lane = t & 63;
    int g = blockIdx.x;
    int sub = (wave << 2) + (lane >> 4);     // 0..15
    int b = lane & 15;
    int s = node_off[g], e = node_off[g + 1];

    float acc[8];
    #pragma unroll
    for (int f = 0; f < 8; f++) acc[f] = 0.0f;

    int i = s + sub;
    for (; i + 16 < e; i += 32) {
        int id0 = snp_ids[i];
        int id1 = snp_ids[i + 16];
        float v0 = bf1(snpT[(size_t)id0 * 16 + b]);
        float v1 = bf1(snpT[(size_t)id1 * 16 + b]);
        uint4 F0 = *(const uint4*)(filtT + (size_t)id0 * 8);
        uint4 F1 = *(const uint4*)(filtT + (size_t)id1 * 8);
        acc[0] += v0 * bflo(F0.x) + v1 * bflo(F1.x);
        acc[1] += v0 * bfhi(F0.x) + v1 * bfhi(F1.x);
        acc[2] += v0 * bflo(F0.y) + v1 * bflo(F1.y);
        acc[3] += v0 * bfhi(F0.y) + v1 * bfhi(F1.y);
        acc[4] += v0 * bflo(F0.z) + v1 * bflo(F1.z);
        acc[5] += v0 * bfhi(F0.z) + v1 * bfhi(F1.z);
        acc[6] += v0 * bflo(F0.w) + v1 * bflo(F1.w);
        acc[7] += v0 * bfhi(F0.w) + v1 * bfhi(F1.w);
    }
    if (i < e) {
        int id0 = snp_ids[i];
        float v0 = bf1(snpT[(size_t)id0 * 16 + b]);
        uint4 F0 = *(const uint4*)(filtT + (size_t)id0 * 8);
        acc[0] += v0 * bflo(F0.x); acc[1] += v0 * bfhi(F0.x);
        acc[2] += v0 * bflo(F0.y); acc[3] += v0 * bfhi(F0.y);
        acc[4] += v0 * bflo(F0.z); acc[5] += v0 * bfhi(F0.z);
        acc[6] += v0 * bflo(F0.w); acc[7] += v0 * bfhi(F0.w);
    }
    #pragma unroll
    for (int f = 0; f < 8; f++) {
        acc[f] += __shfl_xor(acc[f], 16, 64);
        acc[f] += __shfl_xor(acc[f], 32, 64);
    }
    if (lane < 16) {   // lane == b
        float* dst = &sZ[wave][lane * 8];
        *(float4*)(dst)     = make_float4(acc[0], acc[1], acc[2], acc[3]);
        *(float4*)(dst + 4) = make_float4(acc[4], acc[5], acc[6], acc[7]);
    }
    __syncthreads();
    if (t < 128) {
        float val = sZ[0][t] + sZ[1][t] + sZ[2][t] + sZ[3][t];
        h_bf[(size_t)g * 128 + t] = f2bf(val);
    }
}

// ---------------------------------------------------------------------------
// Fused GIN layer 1: chunked agg (bf16, L2-resident slice) + MLP.
// Block = 16 genes x 16 threads; chunk = blockIdx&3. Per gene: 2 edge-halves
// (stride-2 interleave) x 8 col-positions. half combine via shfl_xor(8),
// col-half (fh) exchange via shfl_xor(1). MLP j-split over 4 threads/row.
__global__ __launch_bounds__(256) void k_gin1(const u16* __restrict__ hin,   // [g][128]
                                              u16* __restrict__ hout,        // [g][128]
                                              const int* __restrict__ csr_off,
                                              const int* __restrict__ csr_src,
                                              const float* __restrict__ eps_l,
                                              const float* __restrict__ W1,
                                              const float* __restrict__ b1,
                                              const float* __restrict__ g1,
                                              const float* __restrict__ bt1,
                                              const float* __restrict__ W2,
                                              const float* __restrict__ b2,
                                              const float* __restrict__ g2,
                                              const float* __restrict__ bt2) {
    __shared__ float sW1[128], sb1[16], sg1[16], sbt1[16];
    __shared__ float sW2[128], sb2[8], sg2[8], sbt2[8];
    int t = threadIdx.x;
    if (t < 128) { sW1[t] = W1[t]; sW2[t] = W2[t]; }
    if (t < 16)  { sb1[t] = b1[t]; sg1[t] = g1[t]; sbt1[t] = bt1[t]; }
    if (t < 8)   { sb2[t] = b2[t]; sg2[t] = g2[t]; sbt2[t] = bt2[t]; }

    int chunk = blockIdx.x & 3;
    int g = (blockIdx.x >> 2) * 16 + (t >> 4);
    int u = t & 15;
    int half = u >> 3;                       // edge-range half
    int colpos = u & 7;
    int fh = colpos & 1;                     // f-half: 0 -> f0..3, 1 -> f4..7
    int jgroup = half * 2 + fh;              // 0..3, MLP hidden-unit group
    int col = chunk * 32 + colpos * 4;
    const u16* __restrict__ hc = hin + col;
    float epsv = 1.0f + eps_l[0];

    float a0, a1, a2, a3;
    if (half == 0) {   // self term only once
        uint2 su = *(const uint2*)(hc + (size_t)g * 128);
        a0 = bflo(su.x) * epsv; a1 = bfhi(su.x) * epsv;
        a2 = bflo(su.y) * epsv; a3 = bfhi(su.y) * epsv;
    } else {
        a0 = a1 = a2 = a3 = 0.0f;
    }

    int s = csr_off[g], e = csr_off[g + 1];
    int k = s + half;
    for (; k + 14 < e; k += 16) {   // 8 edges per half, stride 2
        int i0 = csr_src[k],      i1 = csr_src[k + 2];
        int i2 = csr_src[k + 4],  i3 = csr_src[k + 6];
        int i4 = csr_src[k + 8],  i5 = csr_src[k + 10];
        int i6 = csr_src[k + 12], i7 = csr_src[k + 14];
        uint2 v0 = *(const uint2*)(hc + (size_t)i0 * 128);
        uint2 v1 = *(const uint2*)(hc + (size_t)i1 * 128);
        uint2 v2 = *(const uint2*)(hc + (size_t)i2 * 128);
        uint2 v3 = *(const uint2*)(hc + (size_t)i3 * 128);
        uint2 v4 = *(const uint2*)(hc + (size_t)i4 * 128);
        uint2 v5 = *(const uint2*)(hc + (size_t)i5 * 128);
        uint2 v6 = *(const uint2*)(hc + (size_t)i6 * 128);
        uint2 v7 = *(const uint2*)(hc + (size_t)i7 * 128);
        a0 += ((bflo(v0.x) + bflo(v1.x)) + (bflo(v2.x) + bflo(v3.x)))
            + ((bflo(v4.x) + bflo(v5.x)) + (bflo(v6.x) + bflo(v7.x)));
        a1 += ((bfhi(v0.x) + bfhi(v1.x)) + (bfhi(v2.x) + bfhi(v3.x)))
            + ((bfhi(v4.x) + bfhi(v5.x)) + (bfhi(v6.x) + bfhi(v7.x)));
        a2 += ((bflo(v0.y) + bflo(v1.y)) + (bflo(v2.y) + bflo(v3.y)))
            + ((bflo(v4.y) + bflo(v5.y)) + (bflo(v6.y) + bflo(v7.y)));
        a3 += ((bfhi(v0.y) + bfhi(v1.y)) + (bfhi(v2.y) + bfhi(v3.y)))
            + ((bfhi(v4.y) + bfhi(v5.y)) + (bfhi(v6.y) + bfhi(v7.y)));
    }
    for (; k < e; k += 2) {
        int i0 = csr_src[k];
        uint2 v0 = *(const uint2*)(hc + (size_t)i0 * 128);
        a0 += bflo(v0.x); a1 += bfhi(v0.x);
        a2 += bflo(v0.y); a3 += bfhi(v0.y);
    }
    __syncthreads();   // weights visible

    // combine edge halves (lane bit 3)
    a0 += __shfl_xor(a0, 8, 64);
    a1 += __shfl_xor(a1, 8, 64);
    a2 += __shfl_xor(a2, 8, 64);
    a3 += __shfl_xor(a3, 8, 64);
    // exchange col-halves (lane bit 0) to build full z[8]
    float p0 = __shfl_xor(a0, 1, 64);
    float p1 = __shfl_xor(a1, 1, 64);
    float p2 = __shfl_xor(a2, 1, 64);
    float p3 = __shfl_xor(a3, 1, 64);
    float z[8];
    z[fh * 4 + 0] = a0; z[fh * 4 + 1] = a1; z[fh * 4 + 2] = a2; z[fh * 4 + 3] = a3;
    z[(1 - fh) * 4 + 0] = p0; z[(1 - fh) * 4 + 1] = p1;
    z[(1 - fh) * 4 + 2] = p2; z[(1 - fh) * 4 + 3] = p3;

    // split-j MLP: this thread handles hidden units j in [jgroup*4, jgroup*4+4)
    float op[8];
    #pragma unroll
    for (int f = 0; f < 8; f++) op[f] = (jgroup == 0) ? sb2[f] : 0.0f;
    #pragma unroll
    for (int jj = 0; jj < 4; jj++) {
        int j = jgroup * 4 + jj;
        float s1 = sb1[j];
        #pragma unroll
        for (int i2 = 0; i2 < 8; i2++) s1 += z[i2] * sW1[i2 * 16 + j];
        s1 = s1 * BN_SCALE * sg1[j] + sbt1[j];
        s1 = gelu_erf(s1);
        #pragma unroll
        for (int f = 0; f < 8; f++) op[f] += s1 * sW2[j * 8 + f];
    }
    // combine partial outputs over the 4 row-threads, finalize own 4 f's
    float r[4];
    #pragma unroll
    for (int fi = 0; fi < 4; fi++) {
        int f = fh * 4 + fi;
        float x = op[f] + __shfl_xor(op[f], 1, 64);
        x += __shfl_xor(x, 8, 64);
        r[fi] = gelu_erf(x * BN_SCALE * sg2[f] + sbt2[f]);
    }
    if (half == 0) {
        uint2 ou;
        ou.x = pack2(r[0], r[1]); ou.y = pack2(r[2], r[3]);
        *(uint2*)(hout + (size_t)g * 128 + col) = ou;
    }
}

// ---------------------------------------------------------------------------
// Fused GIN layer 2 + attentive readout (no atomics; per-block partials).
__global__ __launch_bounds__(256) void k_gin2(const u16* __restrict__ hin,
                                              const int* __restrict__ csr_off,
                                              const int* __restrict__ csr_src,
                                              const float* __restrict__ eps_l,
                                              const float* __restrict__ W1,
                                              const float* __restrict__ b1,
                                              const float* __restrict__ g1,
                                              const float* __restrict__ bt1,
                                              const float* __restrict__ W2,
                                              const float* __restrict__ b2,
                                              const float* __restrict__ g2,
                                              const float* __restrict__ bt2,
                                              const float* __restrict__ Wk,
                                              const float* __restrict__ bk,
                                              const float* __restrict__ Wq,
                                              const float* __restrict__ Wv,
                                              const float* __restrict__ bv,
                                              float* __restrict__ w_out,    // [b][g]
                                              float* __restrict__ partial) { // [NBLK2][32]
    __shared__ float sW1[128], sb1[16], sg1[16], sbt1[16];
    __shared__ float sW2[128], sb2[8], sg2[8], sbt2[8];
    __shared__ float sWk[64], sWv[64], sbk[8], sbv[8], sWq[8];
    __shared__ float sRed[4][4][8];
    int t = threadIdx.x;
    if (t < 128) { sW1[t] = W1[t]; sW2[t] = W2[t]; }
    if (t < 64)  { sWk[t] = Wk[t]; sWv[t] = Wv[t]; }
    if (t < 16)  { sb1[t] = b1[t]; sg1[t] = g1[t]; sbt1[t] = bt1[t]; }
    if (t < 8)   { sb2[t] = b2[t]; sg2[t] = g2[t]; sbt2[t] = bt2[t];
                   sbk[t] = bk[t]; sbv[t] = bv[t]; sWq[t] = Wq[t]; }

    int chunk = blockIdx.x & 3;
    int g = (blockIdx.x >> 2) * 16 + (t >> 4);
    int u = t & 15;
    int half = u >> 3;
    int colpos = u & 7;
    int fh = colpos & 1;
    int jgroup = half * 2 + fh;
    int b = chunk * 4 + (colpos >> 1);
    int col = chunk * 32 + colpos * 4;
    const u16* __restrict__ hc = hin + col;
    float epsv = 1.0f + eps_l[0];

    float a0, a1, a2, a3;
    if (half == 0) {
        uint2 su = *(const uint2*)(hc + (size_t)g * 128);
        a0 = bflo(su.x) * epsv; a1 = bfhi(su.x) * epsv;
        a2 = bflo(su.y) * epsv; a3 = bfhi(su.y) * epsv;
    } else {
        a0 = a1 = a2 = a3 = 0.0f;
    }

    int s = csr_off[g], e = csr_off[g + 1];
    int k = s + half;
    for (; k + 14 < e; k += 16) {
        int i0 = csr_src[k],      i1 = csr_src[k + 2];
        int i2 = csr_src[k + 4],  i3 = csr_src[k + 6];
        int i4 = csr_src[k + 8],  i5 = csr_src[k + 10];
        int i6 = csr_src[k + 12], i7 = csr_src[k + 14];
        uint2 v0 = *(const uint2*)(hc + (size_t)i0 * 128);
        uint2 v1 = *(const uint2*)(hc + (size_t)i1 * 128);
        uint2 v2 = *(const uint2*)(hc + (size_t)i2 * 128);
        uint2 v3 = *(const uint2*)(hc + (size_t)i3 * 128);
        uint2 v4 = *(const uint2*)(hc + (size_t)i4 * 128);
        uint2 v5 = *(const uint2*)(hc + (size_t)i5 * 128);
        uint2 v6 = *(const uint2*)(hc + (size_t)i6 * 128);
        uint2 v7 = *(const uint2*)(hc + (size_t)i7 * 128);
        a0 += ((bflo(v0.x) + bflo(v1.x)) + (bflo(v2.x) + bflo(v3.x)))
            + ((bflo(v4.x) + bflo(v5.x)) + (bflo(v6.x) + bflo(v7.x)));
        a1 += ((bfhi(v0.x) + bfhi(v1.x)) + (bfhi(v2.x) + bfhi(v3.x)))
            + ((bfhi(v4.x) + bfhi(v5.x)) + (bfhi(v6.x) + bfhi(v7.x)));
        a2 += ((bflo(v0.y) + bflo(v1.y)) + (bflo(v2.y) + bflo(v3.y)))
            + ((bflo(v4.y) + bflo(v5.y)) + (bflo(v6.y) + bflo(v7.y)));
        a3 += ((bfhi(v0.y) + bfhi(v1.y)) + (bfhi(v2.y) + bfhi(v3.y)))
            + ((bfhi(v4.y) + bfhi(v5.y)) + (bfhi(v6.y) + bfhi(v7.y)));
    }
    for (; k < e; k += 2) {
        int i0 = csr_src[k];
        uint2 v0 = *(const uint2*)(hc + (size_t)i0 * 128);
        a0 += bflo(v0.x); a1 += bfhi(v0.x);
        a2 += bflo(v0.y); a3 += bfhi(v0.y);
    }
    __syncthreads();

    a0 += __shfl_xor(a0, 8, 64);
    a1 += __shfl_xor(a1, 8, 64);
    a2 += __shfl_xor(a2, 8, 64);
    a3 += __shfl_xor(a3, 8, 64);
    float p0 = __shfl_xor(a0, 1, 64);
    float p1 = __shfl_xor(a1, 1, 64);
    float p2 = __shfl_xor(a2, 1, 64);
    float p3 = __shfl_xor(a3, 1, 64);
    float z[8];
    z[fh * 4 + 0] = a0; z[fh * 4 + 1] = a1; z[fh * 4 + 2] = a2; z[fh * 4 + 3] = a3;
    z[(1 - fh) * 4 + 0] = p0; z[(1 - fh) * 4 + 1] = p1;
    z[(1 - fh) * 4 + 2] = p2; z[(1 - fh) * 4 + 3] = p3;

    // split-j MLP (4 hidden units per thread)
    float op[8];
    #pragma unroll
    for (int f = 0; f < 8; f++) op[f] = (jgroup == 0) ? sb2[f] : 0.0f;
    #pragma unroll
    for (int jj = 0; jj < 4; jj++) {
        int j = jgroup * 4 + jj;
        float s1 = sb1[j];
        #pragma unroll
        for (int i2 = 0; i2 < 8; i2++) s1 += z[i2] * sW1[i2 * 16 + j];
        s1 = s1 * BN_SCALE * sg1[j] + sbt1[j];
        s1 = gelu_erf(s1);
        #pragma unroll
        for (int f = 0; f < 8; f++) op[f] += s1 * sW2[j * 8 + f];
    }
    // combine, finalize own f-half, exchange to get full hv[8]
    float hvh[4];
    #pragma unroll
    for (int fi = 0; fi < 4; fi++) {
        int f = fh * 4 + fi;
        float x = op[f] + __shfl_xor(op[f], 1, 64);
        x += __shfl_xor(x, 8, 64);
        hvh[fi] = gelu_erf(x * BN_SCALE * sg2[f] + sbt2[f]);
    }
    float hv[8];
    #pragma unroll
    for (int fi = 0; fi < 4; fi++) {
        hv[fh * 4 + fi] = hvh[fi];
        hv[(1 - fh) * 4 + fi] = __shfl_xor(hvh[fi], 1, 64);
    }

    // readout: q split over 4 threads (2 j's each)
    float qp = 0.0f;
    #pragma unroll
    for (int jj = 0; jj < 2; jj++) {
        int j = jgroup * 2 + jj;
        float key = sbk[j];
        #pragma unroll
        for (int i2 = 0; i2 < 8; i2++) key += hv[i2] * sWk[i2 * 8 + j];
        qp += key * sWq[j];
    }
    float q = qp + __shfl_xor(qp, 1, 64);
    q += __shfl_xor(q, 8, 64);
    float w = sigmoidf_(q);
    if (fh == 0 && half == 0) w_out[(size_t)b * NGENES + g] = w;

    // value contribution: own f-half; half 1 zeroed (avoid double count)
    float contrib[4];
    #pragma unroll
    for (int fi = 0; fi < 4; fi++) {
        int f = fh * 4 + fi;
        float v = sbv[f];
        #pragma unroll
        for (int i2 = 0; i2 < 8; i2++) v += hv[i2] * sWv[i2 * 8 + f];
        contrib[fi] = (half == 0) ? v * w : 0.0f;
    }
    // reduce over halves (xor8) and the 4 genes in the wave (xor 16,32)
    #pragma unroll
    for (int fi = 0; fi < 4; fi++) {
        contrib[fi] += __shfl_xor(contrib[fi], 8, 64);
        contrib[fi] += __shfl_xor(contrib[fi], 16, 64);
        contrib[fi] += __shfl_xor(contrib[fi], 32, 64);
    }
    int wave = t >> 6, lane = t & 63;
    if (lane < 8) {
        #pragma unroll
        for (int fi = 0; fi < 4; fi++)
            sRed[wave][lane >> 1][(lane & 1) * 4 + fi] = contrib[fi];
    }
    __syncthreads();
    if (t < 32) {   // 4 local batches x 8 filters -> plain store (NO atomics)
        int bl = t >> 3, f = t & 7;
        float sm = sRed[0][bl][f] + sRed[1][bl][f] + sRed[2][bl][f] + sRed[3][bl][f];
        partial[(size_t)blockIdx.x * 32 + bl * 8 + f] = sm;
    }
}

// ---------------------------------------------------------------------------
// Parallel reduction of partial[NBLK2][32] -> g_h[128].
// One block per (b,f) output; 64 lanes stride the 1250 blocks of that chunk.
__global__ __launch_bounds__(64) void k_reduce(const float* __restrict__ partial,
                                               float* __restrict__ g_h) {
    int bf = blockIdx.x;            // 0..127 = b*8+f
    int b = bf >> 3, f = bf & 7;
    int c = b >> 2, bl = b & 3;
    int ln = threadIdx.x;
    float s = 0.0f;
    for (int j = ln; j < NBLK2 / 4; j += 64)     // 1250 rows per chunk
        s += partial[(size_t)(c + 4 * j) * 32 + bl * 8 + f];
    #pragma unroll
    for (int m = 1; m < 64; m <<= 1) s += __shfl_xor(s, m, 64);
    if (ln == 0) g_h[bf] = s;
}

// ---------------------------------------------------------------------------
// Head MLP (reads pre-reduced g_h[128]).
__global__ __launch_bounds__(1024) void k_head(const float* __restrict__ g_h,
                                               const float* __restrict__ Wp1, const float* __restrict__ bp1,
                                               const float* __restrict__ gp1, const float* __restrict__ btp1,
                                               const float* __restrict__ Wp2, const float* __restrict__ bp2,
                                               const float* __restrict__ gp2, const float* __restrict__ btp2,
                                               const float* __restrict__ Wp3, const float* __restrict__ bp3,
                                               float* __restrict__ preds) {
    __shared__ float sgh[128];
    __shared__ float z1[16 * 64];
    __shared__ float z2[16 * 16];
    int t = threadIdx.x;
    if (t < 128) sgh[t] = g_h[t];
    __syncthreads();
    {
        int b = t >> 6, j = t & 63;
        float s = bp1[j];
        #pragma unroll
        for (int k = 0; k < 8; k++) s += sgh[b * 8 + k] * Wp1[k * 64 + j];
        s = s * BN_SCALE * gp1[j] + btp1[j];
        z1[b * 64 + j] = gelu_erf(s);
    }
    __syncthreads();
    if (t < 256) {
        int b = t >> 4, j = t & 15;
        float s = bp2[j];
        for (int k = 0; k < 64; k++) s += z1[b * 64 + k] * Wp2[k * 16 + j];
        s = s * BN_SCALE * gp2[j] + btp2[j];
        z2[b * 16 + j] = gelu_erf(s);
    }
    __syncthreads();
    if (t < 16) {
        float s = bp3[0];
        #pragma unroll
        for (int k = 0; k < 16; k++) s += z2[t * 16 + k] * Wp3[k];
        preds[t] = s;
    }
}

// ---------------------------------------------------------------------------
extern "C" void kernel_launch(void* const* d_in, const int* in_sizes, int n_in,
                              void* d_out, int out_size, void* d_ws, size_t ws_size,
                              hipStream_t stream) {
    const float* snp          = (const float*)d_in[0];
    const int*   snp_ids      = (const int*)  d_in[1];
    const int*   gene_of_node = (const int*)  d_in[2];
    const int*   edge_src     = (const int*)  d_in[3];
    const int*   edge_dst     = (const int*)  d_in[4];
    const float* filters      = (const float*)d_in[5];
    const float* eps          = (const float*)d_in[6];
    const float* W1  = (const float*)d_in[7];
    const float* b1  = (const float*)d_in[8];
    const float* g1  = (const float*)d_in[9];
    const float* bt1 = (const float*)d_in[10];
    const float* W2  = (const float*)d_in[11];
    const float* b2  = (const float*)d_in[12];
    const float* g2  = (const float*)d_in[13];
    const float* bt2 = (const float*)d_in[14];
    const float* Wk  = (const float*)d_in[15];
    const float* bk  = (const float*)d_in[16];
    const float* Wq  = (const float*)d_in[17];
    const float* Wv  = (const float*)d_in[18];
    const float* bv  = (const float*)d_in[19];
    const float* Wp1 = (const float*)d_in[20];
    const float* bp1 = (const float*)d_in[21];
    const float* gp1 = (const float*)d_in[22];
    const float* btp1= (const float*)d_in[23];
    const float* Wp2 = (const float*)d_in[24];
    const float* bp2 = (const float*)d_in[25];
    const float* gp2 = (const float*)d_in[26];
    const float* btp2= (const float*)d_in[27];
    const float* Wp3 = (const float*)d_in[28];
    const float* bp3 = (const float*)d_in[29];

    float* out        = (float*)d_out;
    float* out_preds  = out;
    float* out_filt   = out + 16;
    float* out_w      = out + 16 + NFILT * NSNPS;

    // ---- workspace layout
    char* ws = (char*)d_ws;
    size_t off = 0;
    u16* snpT = (u16*)(ws + off); off += (size_t)NSNPS * 16 * 2;                 // 16 MB
    u16* filtT= (u16*)(ws + off); off += (size_t)NSNPS * 8 * 2;                  // 8 MB
    u16* h0   = (u16*)(ws + off); off += (size_t)NGENES * 128 * 2;               // 5.12 MB
    u16* h1   = (u16*)(ws + off); off += (size_t)NGENES * 128 * 2;               // 5.12 MB
    int* node_off = (int*)(ws + off); off += ((NGENES + 1) * 4 + 255) / 256 * 256;
    int* deg      = (int*)(ws + off); off += (NGENES * 4 + 255) / 256 * 256;
    int* csr_off  = (int*)(ws + off); off += ((NGENES + 1) * 4 + 255) / 256 * 256;
    int* cursor   = (int*)(ws + off); off += (NGENES * 4 + 255) / 256 * 256;
    int* csr_src  = (int*)(ws + off); off += (size_t)NEDGES * 4;
    float* partial= (float*)(ws + off); off += (size_t)NBLK2 * 32 * 4;           // 640 KB
    float* g_h    = (float*)(ws + off); off += 512;

    // 1. fused prep (filtersT + fp32 copy, snpT, node_off + deg zeroing)
    k_prep<<<PREP_NA + PREP_NB + PREP_NC, 256, 0, stream>>>(
        snp, filters, gene_of_node, snpT, filtT, out_filt, node_off, deg);
    // 2. CSR build
    k_deg<<<(NEDGES + 255) / 256, 256, 0, stream>>>(edge_dst, deg);
    k_scan<<<1, 1024, 0, stream>>>(deg, csr_off, cursor);
    k_scatter<<<(NEDGES + 255) / 256, 256, 0, stream>>>(edge_src, edge_dst, cursor, csr_src);
    // 3. SNP -> gene readout (4 waves/gene)
    k_snp2gene<<<NGENES, 256, 0, stream>>>(snpT, snp_ids, node_off, filtT, h0);
    // 4. GIN layer 1 (16 threads/gene: edge-halved gather + split-j MLP)
    k_gin1<<<NBLK2, 256, 0, stream>>>(h0, h1, csr_off, csr_src, eps + 0,
                                      W1 + 0 * 128, b1 + 0 * 16, g1 + 0 * 16, bt1 + 0 * 16,
                                      W2 + 0 * 128, b2 + 0 * 8, g2 + 0 * 8, bt2 + 0 * 8);
    // 5. GIN layer 2 + attentive readout (no atomics)
    k_gin2<<<NBLK2, 256, 0, stream>>>(h1, csr_off, csr_src, eps + 1,
                                      W1 + 1 * 128, b1 + 1 * 16, g1 + 1 * 16, bt1 + 1 * 16,
                                      W2 + 1 * 128, b2 + 1 * 8, g2 + 1 * 8, bt2 + 1 * 8,
                                      Wk, bk, Wq, Wv, bv, out_w, partial);
    // 6. parallel partial reduction (128 blocks) + head MLP
    k_reduce<<<128, 64, 0, stream>>>(partial, g_h);
    k_head<<<1, 1024, 0, stream>>>(g_h, Wp1, bp1, gp1, btp1, Wp2, bp2, gp2, btp2, Wp3, bp3, out_preds);
}